// Round 5
// baseline (321.082 us; speedup 1.0000x reference)
//
#include <hip/hip_runtime.h>

// FilterInitializerLinear: conv3x3(512->512, pad1) on (192,512,22,22) fp32,
// PrRoIPool 4x4 per (image,seq) roi, mean over 3 images, /(C*16).
// Image n feeds exactly one roi -> conv computed only on roi-box positions,
// globally compacted (flat-N prefix over all images) for dense block packing.

#define NIMG 192
#define CCH 512
#define FH 22
#define FW 22
#define SPATIAL 484
#define PADH 24
#define PADW 24
#define NTMAX 49152   // worst-case total compacted positions (192 * 256)

typedef __bf16 bf16;
typedef __bf16 bf16x2 __attribute__((ext_vector_type(2)));
typedef __bf16 bf16x8 __attribute__((ext_vector_type(8)));
typedef float f32x4 __attribute__((ext_vector_type(4)));

#define GLOBAL_AS __attribute__((address_space(1)))
#define LDS_AS __attribute__((address_space(3)))

__device__ __forceinline__ void gload_lds16(const void* g, void* l) {
  __builtin_amdgcn_global_load_lds((GLOBAL_AS const void*)g, (LDS_AS void*)l, 16, 0, 0);
}

// boxes[n*8]: {y0, x0, xw, xwp, yh, countp, -, -}; poff = boxes + NIMG*8,
// poff[0..192] prefix sums of countp (poff[192] = NT total).
__global__ void prep_kernel(const float* __restrict__ bb, int* __restrict__ boxes) {
  int n = threadIdx.x;
  if (n < NIMG) {
    const float scale = 1.f / 16.f;
    float x1s = bb[n * 4 + 0] * scale;
    float y1s = bb[n * 4 + 1] * scale;
    float x2s = (bb[n * 4 + 0] + bb[n * 4 + 2]) * scale;
    float y2s = (bb[n * 4 + 1] + bb[n * 4 + 3]) * scale;
    float binx = (x2s - x1s) * 0.25f;
    float biny = (y2s - y1s) * 0.25f;
    float endx = (x1s + 3 * binx) + binx;   // fp-identical to pool's bin-3 end
    float endy = (y1s + 3 * biny) + biny;
    int x0 = max(0, (int)floorf(x1s));
    int xc1 = min(FW - 1, (int)floorf(endx) + 1);
    int y0 = max(0, (int)floorf(y1s));
    int yc1 = min(FH - 1, (int)floorf(endy) + 1);
    int xw = xc1 - x0 + 1;
    int yh = yc1 - y0 + 1;
    int xwp = (xw + 1) & ~1;
    int* b = boxes + n * 8;
    b[0] = y0; b[1] = x0; b[2] = xw; b[3] = xwp; b[4] = yh; b[5] = yh * xwp;
    b[6] = 0; b[7] = 0;
  }
  __syncthreads();
  if (threadIdx.x == 0) {
    int* poff = boxes + NIMG * 8;
    int acc = 0;
    for (int i = 0; i < NIMG; ++i) {
      poff[i] = acc;
      acc += boxes[i * 8 + 5];
    }
    poff[NIMG] = acc;
  }
}

// ---- pass 1: fused. Blocks [0, NIMG*FH): feat fp32 NCHW -> bf16 padded NHWC
// via LDS transpose (rows outside box+halo skipped). Blocks [NIMG*FH, +CCH):
// conv_w (co,ci,3,3) -> Wb[co][pos][ci] bf16.
__global__ __launch_bounds__(256) void cast_pad_kernel(const float* __restrict__ feat,
                                                       bf16* __restrict__ Fp,
                                                       const float* __restrict__ cw,
                                                       bf16* __restrict__ Wb,
                                                       const int* __restrict__ boxes) {
  static __shared__ __align__(16) char smem[CCH * FW * 2];   // 22528 B
  int t = threadIdx.x;
  if (blockIdx.x >= NIMG * FH) {
    int co = blockIdx.x - NIMG * FH;
    float* lw = (float*)smem;
    const float* src = cw + (long)co * CCH * 9;
    #pragma unroll
    for (int k = 0; k < 18; ++k) lw[t + 256 * k] = src[t + 256 * k];
    __syncthreads();
    bf16* dst = Wb + (long)co * 9 * CCH;
    #pragma unroll
    for (int k = 0; k < 18; ++k) {
      int f = t + 256 * k;
      int pos = f >> 9;
      int ci = f & 511;
      dst[f] = (bf16)lw[ci * 9 + pos];
    }
    return;
  }
  bf16* lt = (bf16*)smem;   // [ci][x]
  int n = blockIdx.x / FH;
  int y = blockIdx.x % FH;
  int y0 = boxes[n * 8 + 0];
  int y1 = y0 + boxes[n * 8 + 4] - 1;
  if (y < y0 - 1 || y > y1 + 1) return;
  const float* fb = feat + (long)n * CCH * SPATIAL + y * FW;
  #pragma unroll 4
  for (int k = 0; k < 44; ++k) {            // 512*22 = 11264 = 256*44
    int f = t + 256 * k;
    int ci = f / FW;
    int x = f - ci * FW;
    lt[f] = (bf16)fb[(long)ci * SPATIAL + x];
  }
  __syncthreads();
  uint* od = (uint*)(Fp + (long)(n * PADH + y + 1) * PADW * CCH);
  #pragma unroll 4
  for (int k = 0; k < 24; ++k) {            // 24px * 256 uint = 6144
    int w = t + 256 * k;
    int px = w >> 8;
    int cp = w & 255;
    int ci = cp * 2;
    uint v = 0;
    if (px >= 1 && px <= FW) {
      bf16x2 pr;
      pr[0] = lt[ci * FW + px - 1];
      pr[1] = lt[(ci + 1) * FW + px - 1];
      v = __builtin_bit_cast(uint, pr);
    }
    od[w] = v;
  }
  if (y == 0 || y == FH - 1) {
    int py = (y == 0) ? 0 : PADH - 1;
    uint* oz = (uint*)(Fp + (long)(n * PADH + py) * PADW * CCH);
    #pragma unroll 4
    for (int k = 0; k < 24; ++k) oz[t + 256 * k] = 0u;
  }
}

// ---- pass 2: implicit-GEMM conv on flat compacted positions.
// M=512 (2 co-tiles of 256) x N=NT (128-wide s-tiles), BK=64, 8 waves (4Mx2N),
// 3-deep LDS ring, counted vmcnt(6), T2 XOR swizzle, T5 setprio.
// Grid 768 (worst case); co-tile pairs kept XCD-adjacent (B reads shared).
__global__ __launch_bounds__(512, 2) void conv_kernel(
    const bf16* __restrict__ Fp, const bf16* __restrict__ Wb,
    const float* __restrict__ bias, bf16* __restrict__ O,
    const int* __restrict__ boxes) {
  __shared__ __align__(16) bf16 ring[3 * 24576];   // 144 KiB
  const int* poff = boxes + NIMG * 8;
  int NT = poff[NIMG];
  int b0 = blockIdx.x;
  int p = b0 >> 1;
  int sp = (p & 7) * 48 + (p >> 3);     // bijective XCD swizzle on pairs (384=8*48)
  int bid = sp * 2 + (b0 & 1);
  int st = bid >> 1;
  int mt = bid & 1;
  int s0 = st << 7;
  int co0 = mt << 8;
  if (s0 >= NT) return;   // block-uniform early exit

  int tid = threadIdx.x;
  int wv = tid >> 6, l = tid & 63;
  int wm = wv >> 1, wn = wv & 1;          // 4 M-waves x 2 N-waves, 64x64 each
  int lrow = tid >> 3;                    // 0..63: staged row within 64-row block
  int cg8 = ((tid & 7) ^ (lrow & 7)) << 3;  // inverse-swizzled global chunk (elems)

  long aBase = (long)(co0 + lrow) * 9 * CCH;
  long bRow[2];
  #pragma unroll
  for (int j = 0; j < 2; ++j) {
    int sg = s0 + 64 * j + lrow;
    if (sg > NT - 1) sg = NT - 1;         // dup position; store masked
    // binary search: n s.t. poff[n] <= sg < poff[n+1]
    int lo = 0, hi = NIMG - 1;
    while (lo < hi) {
      int mid = (lo + hi + 1) >> 1;
      if (poff[mid] <= sg) lo = mid; else hi = mid - 1;
    }
    int n = lo;
    int local = sg - poff[n];
    const int* bx = boxes + n * 8;
    int y0 = bx[0], x0 = bx[1], xwp = bx[3];
    int r = local / xwp;
    int c = local - r * xwp;
    int sy = y0 + r, sx = x0 + c;
    bRow[j] = ((long)(n * PADH + sy) * PADW + sx) * CCH + cg8;
  }

  auto STAGE = [&](int t, bf16* bufA, bf16* bufB) {
    int pos = t >> 3;
    int ci0 = (t & 7) << 6;
    int ky = pos / 3;
    int kx = pos - 3 * ky;
    long ao = aBase + (long)pos * CCH + ci0 + cg8;
    #pragma unroll
    for (int j = 0; j < 4; ++j)
      gload_lds16(Wb + ao + (long)j * 64 * 9 * CCH, bufA + j * 4096 + tid * 8);
    long bsh = (long)(ky * PADW + kx) * CCH + ci0;
    #pragma unroll
    for (int j = 0; j < 2; ++j)
      gload_lds16(Fp + bRow[j] + bsh, bufB + j * 4096 + tid * 8);
  };

  int abyte[4], aswz[4], bbyte[4], bswz[4], ccol[2];
  #pragma unroll
  for (int i = 0; i < 4; ++i) {
    int ra = wm * 64 + i * 16 + (l & 15);
    abyte[i] = ra * 128; aswz[i] = (ra & 7) << 4;
    int rb = wn * 64 + i * 16 + (l & 15);
    bbyte[i] = rb * 128; bswz[i] = (rb & 7) << 4;
  }
  ccol[0] = (l >> 4) * 16;
  ccol[1] = 64 + (l >> 4) * 16;

  const f32x4 vz = {0.f, 0.f, 0.f, 0.f};
  f32x4 acc[4][4];
  #pragma unroll
  for (int a = 0; a < 4; ++a)
    #pragma unroll
    for (int b = 0; b < 4; ++b) acc[a][b] = vz;

  auto COMPUTE = [&](const bf16* bufA, const bf16* bufB) {
    bf16x8 af[2][4], bfv[2][4];
    #pragma unroll
    for (int kk = 0; kk < 2; ++kk)
      #pragma unroll
      for (int i = 0; i < 4; ++i) {
        af[kk][i] = *(const bf16x8*)((const char*)bufA + abyte[i] + (ccol[kk] ^ aswz[i]));
        bfv[kk][i] = *(const bf16x8*)((const char*)bufB + bbyte[i] + (ccol[kk] ^ bswz[i]));
      }
    __builtin_amdgcn_s_setprio(1);
    #pragma unroll
    for (int kk = 0; kk < 2; ++kk)
      #pragma unroll
      for (int mi = 0; mi < 4; ++mi)
        #pragma unroll
        for (int nj = 0; nj < 4; ++nj)
          acc[mi][nj] = __builtin_amdgcn_mfma_f32_16x16x32_bf16(
              af[kk][mi], bfv[kk][nj], acc[mi][nj], 0, 0, 0);
    __builtin_amdgcn_s_setprio(0);
  };

  bf16* A0 = ring;          bf16* B0 = A0 + 16384;
  bf16* A1 = ring + 24576;  bf16* B1 = A1 + 16384;
  bf16* A2 = ring + 49152;  bf16* B2 = A2 + 16384;

  STAGE(0, A0, B0);
  STAGE(1, A1, B1);
  asm volatile("s_waitcnt vmcnt(6)" ::: "memory");
  __builtin_amdgcn_s_barrier();

  #pragma unroll 1
  for (int tb = 0; tb < 69; tb += 3) {
    STAGE(tb + 2, A2, B2);
    COMPUTE(A0, B0);
    asm volatile("s_waitcnt vmcnt(6)" ::: "memory");
    __builtin_amdgcn_s_barrier();
    STAGE(tb + 3, A0, B0);
    COMPUTE(A1, B1);
    asm volatile("s_waitcnt vmcnt(6)" ::: "memory");
    __builtin_amdgcn_s_barrier();
    STAGE(tb + 4, A1, B1);
    COMPUTE(A2, B2);
    asm volatile("s_waitcnt vmcnt(6)" ::: "memory");
    __builtin_amdgcn_s_barrier();
  }
  STAGE(71, A2, B2);
  COMPUTE(A0, B0);
  asm volatile("s_waitcnt vmcnt(6)" ::: "memory");
  __builtin_amdgcn_s_barrier();
  COMPUTE(A1, B1);
  asm volatile("s_waitcnt vmcnt(0)" ::: "memory");
  __builtin_amdgcn_s_barrier();
  COMPUTE(A2, B2);

  // epilogue: C/D layout col=lane&15 (s), row=(lane>>4)*4+reg (co).
  // O layout: [co][gp] flat, stride NTMAX. Halo cols hold valid conv values
  // (pool weight is 0 there) so no masking beyond s < NT.
  #pragma unroll
  for (int nj = 0; nj < 4; ++nj) {
    int s = s0 + wn * 64 + nj * 16 + (l & 15);
    bool ok = (s < NT);
    #pragma unroll
    for (int mi = 0; mi < 4; ++mi) {
      #pragma unroll
      for (int rr = 0; rr < 4; ++rr) {
        if (ok) {
          int co = co0 + wm * 64 + mi * 16 + (l >> 4) * 4 + rr;
          float v = acc[mi][nj][rr] + bias[co];
          O[(long)co * NTMAX + s] = (bf16)v;
        }
      }
    }
  }
}

// ---- pass 3: PrRoIPool over flat O + mean over images + /(C*16).
// grid = 64 seqs * 8 c-chunks (512 blocks, 1 wave each).
__global__ __launch_bounds__(64) void pool_kernel(const bf16* __restrict__ O,
                                                  const float* __restrict__ bb,
                                                  const int* __restrict__ boxes,
                                                  float* __restrict__ out) {
  __shared__ float wys[4][FH];
  __shared__ float wxs[4][24];
  const int* poff = boxes + NIMG * 8;
  int ns = blockIdx.x >> 3;
  int chunk = blockIdx.x & 7;
  int lane = threadIdx.x;
  int c = chunk * 64 + lane;
  f32x4 acc[4];
  #pragma unroll
  for (int p = 0; p < 4; ++p) acc[p] = (f32x4){0.f, 0.f, 0.f, 0.f};

  for (int ni = 0; ni < 3; ++ni) {
    int n = ni * 64 + ns;
    __syncthreads();
    if (lane < 8) {
      int t = lane;
      int axis = t >> 2;
      int p = t & 3;
      const float scale = 1.f / 16.f;
      float bxv = bb[n * 4 + 0], byv = bb[n * 4 + 1];
      float bwv = bb[n * 4 + 2], bhv = bb[n * 4 + 3];
      float s1 = (axis ? bxv : byv) * scale;
      float s2 = ((axis ? bxv : byv) + (axis ? bwv : bhv)) * scale;
      float blen = (s2 - s1) * 0.25f;
      float start = s1 + p * blen;
      float end = start + blen;
      float inv = 1.0f / blen;          // folds 1/area into the weights
      float* wrow = axis ? &wxs[p][0] : &wys[p][0];
      int size = axis ? FW : FH;
      int zn = axis ? 24 : FH;
      for (int i = 0; i < zn; ++i) wrow[i] = 0.f;
      int s0i = (int)floorf(start);
      for (int k = 0; k < 6; ++k) {
        int cell = s0i + k;
        float cf = (float)cell;
        float a1 = fmaxf(start, cf);
        float a2 = fmaxf(fminf(end, cf + 1.f), a1);
        float alpha = a1 - cf, lim = a2 - cf;
        float f0 = (lim - 0.5f * lim * lim) - (alpha - 0.5f * alpha * alpha);
        float f1 = 0.5f * lim * lim - 0.5f * alpha * alpha;
        if (cell >= 0 && cell < size) wrow[cell] += f0 * inv;
        if (cell + 1 >= 0 && cell + 1 < size) wrow[cell + 1] += f1 * inv;
      }
    }
    __syncthreads();
    const int* bxp = boxes + n * 8;
    int y0 = bxp[0], x0 = bxp[1], xwp = bxp[3], yh = bxp[4];
    const bf16* Op = O + (long)c * NTMAX + poff[n];
    int khalf = xwp >> 1;
    for (int rr = 0; rr < yh; ++rr) {
      int y = y0 + rr;
      float w0 = wys[0][y], w1 = wys[1][y], w2 = wys[2][y], w3 = wys[3][y];
      const uint* rp = (const uint*)(Op + rr * xwp);
      for (int k = 0; k < khalf; ++k) {
        uint u = rp[k];
        bf16x2 pr = __builtin_bit_cast(bf16x2, u);
        #pragma unroll
        for (int h = 0; h < 2; ++h) {
          int j = x0 + 2 * k + h;        // absolute x; halo col weight is 0
          float v = (float)pr[h];
          float x0w = wxs[0][j], x1w = wxs[1][j], x2w = wxs[2][j], x3w = wxs[3][j];
          float t0 = w0 * v, t1 = w1 * v, t2 = w2 * v, t3 = w3 * v;
          acc[0][0] += t0 * x0w; acc[0][1] += t0 * x1w; acc[0][2] += t0 * x2w; acc[0][3] += t0 * x3w;
          acc[1][0] += t1 * x0w; acc[1][1] += t1 * x1w; acc[1][2] += t1 * x2w; acc[1][3] += t1 * x3w;
          acc[2][0] += t2 * x0w; acc[2][1] += t2 * x1w; acc[2][2] += t2 * x2w; acc[2][3] += t2 * x3w;
          acc[3][0] += t3 * x0w; acc[3][1] += t3 * x1w; acc[3][2] += t3 * x2w; acc[3][3] += t3 * x3w;
        }
      }
    }
  }
  const float fin = 1.f / (3.f * 512.f * 16.f);
  float* outp = out + ((long)(ns * CCH + c)) * 16;
  #pragma unroll
  for (int p = 0; p < 4; ++p) {
    f32x4 v = acc[p] * fin;
    *(f32x4*)(outp + p * 4) = v;
  }
}

extern "C" void kernel_launch(void* const* d_in, const int* in_sizes, int n_in,
                              void* d_out, int out_size, void* d_ws, size_t ws_size,
                              hipStream_t stream) {
  const float* feat = (const float*)d_in[0];
  const float* bb = (const float*)d_in[1];
  const float* cw = (const float*)d_in[2];
  const float* cb = (const float*)d_in[3];
  float* out = (float*)d_out;

  const size_t FP_BYTES = (size_t)NIMG * PADH * PADW * CCH * 2;     // 113,246,208
  const size_t WB_BYTES = (size_t)CCH * 9 * CCH * 2;                //   4,718,592
  const size_t O_BYTES = (size_t)CCH * NTMAX * 2;                   //  50,331,648
  const size_t BOX_BYTES = (size_t)(NIMG * 8 + NIMG + 8) * 4;
  if (ws_size < FP_BYTES + WB_BYTES + O_BYTES + BOX_BYTES) return;

  char* ws = (char*)d_ws;
  bf16* Fp = (bf16*)ws;
  bf16* Wb = (bf16*)(ws + FP_BYTES);
  bf16* O = (bf16*)(ws + FP_BYTES + WB_BYTES);
  int* boxes = (int*)(ws + FP_BYTES + WB_BYTES + O_BYTES);

  hipLaunchKernelGGL(prep_kernel, dim3(1), dim3(256), 0, stream, bb, boxes);
  hipLaunchKernelGGL(cast_pad_kernel, dim3(NIMG * FH + CCH), dim3(256), 0, stream,
                     feat, Fp, cw, Wb, boxes);
  hipLaunchKernelGGL(conv_kernel, dim3(768), dim3(512), 0, stream, Fp, Wb, cb, O, boxes);
  hipLaunchKernelGGL(pool_kernel, dim3(64 * 8), dim3(64), 0, stream, O, bb, boxes, out);
}